// Round 5
// baseline (178.276 us; speedup 1.0000x reference)
//
#include <hip/hip_runtime.h>
#include <math.h>

#define M_ 4
#define A_ 256
#define RBF_ 64
#define F_ 32
#define H_ 32
#define SI_ 32
#define TF_ 128   // 4 tags * F

typedef __attribute__((ext_vector_type(8))) short bf16x8;
typedef __attribute__((ext_vector_type(4))) float f32x4;

__device__ __forceinline__ unsigned short f2bf(float f) {
  union { float f; unsigned u; } v; v.f = f;
  unsigned r = v.u + 0x7FFFu + ((v.u >> 16) & 1u);   // RNE bf16 (weights, one-time)
  return (unsigned short)(r >> 16);
}

// pack two fp32 -> two bf16 (round-half-up: +0x8000 then take hi16) in 3 VALU
__device__ __forceinline__ unsigned pack2bf(float lo, float hi) {
  union { float f; unsigned u; } a, b; a.f = lo; b.f = hi;
  return __builtin_amdgcn_perm(b.u + 0x8000u, a.u + 0x8000u, 0x07060302u);
}

__device__ __forceinline__ float sspf(float x) {
  // log(0.5*exp(x)+0.5) = softplus(x) - ln2, numerically stable
  return fmaxf(x, 0.f) + log1pf(expf(-fabsf(x))) - 0.6931471805599453f;
}

// ---------------------------------------------------------------------------
// Setup: collapse the two linear Dense layers per tag into one 64x32 map.
// ws layout: WcT bf16 [tf=128][k=64] (16384 B), then bc fp32 [128] at +16384.
// tf = tag*32 + f, tag order {00,01,10,11}.
// ---------------------------------------------------------------------------
__global__ __launch_bounds__(256) void combine_weights(
    const float* __restrict__ w1_00, const float* __restrict__ b1_00,
    const float* __restrict__ w2_00, const float* __restrict__ b2_00,
    const float* __restrict__ w1_01, const float* __restrict__ b1_01,
    const float* __restrict__ w2_01, const float* __restrict__ b2_01,
    const float* __restrict__ w1_10, const float* __restrict__ b1_10,
    const float* __restrict__ w2_10, const float* __restrict__ b2_10,
    const float* __restrict__ w1_11, const float* __restrict__ b1_11,
    const float* __restrict__ w2_11, const float* __restrict__ b2_11,
    unsigned short* __restrict__ wsT, float* __restrict__ bcw)
{
  const float* w1s[4] = {w1_00, w1_01, w1_10, w1_11};
  const float* b1s[4] = {b1_00, b1_01, b1_10, b1_11};
  const float* w2s[4] = {w2_00, w2_01, w2_10, w2_11};
  const float* b2s[4] = {b2_00, b2_01, b2_10, b2_11};
  int tid = blockIdx.x * 256 + threadIdx.x;    // 0..8191
  int k   = tid >> 7;
  int tf  = tid & 127;
  int tag = tf >> 5, f = tf & 31;
  const float* w1 = w1s[tag];
  const float* w2 = w2s[tag];
  float s = 0.f;
  for (int h = 0; h < H_; ++h) s += w1[k * H_ + h] * w2[h * F_ + f];
  wsT[tf * 64 + k] = f2bf(s);                  // transposed for B-frag loads
  if (tid < TF_) {
    const float* b1 = b1s[tag];
    const float* b2 = b2s[tag];
    float sb = b2[f];
    for (int h = 0; h < H_; ++h) sb += b1[h] * w2[h * F_ + f];
    bcw[tf] = sb;                              // bias stays fp32
  }
}

// ---------------------------------------------------------------------------
// Main fused kernel: one block per (m,a), 4 waves, wave-specialized by tag.
//  Wave role: which = w&1; pairsel = ((w>>1)^block)&1 selects tag pair
//  {00,11} (pair 0) or {01,10} (pair 1). Each wave computes R for its two
//  ct = tag*2+which tf-tiles over ALL 16 b-tiles, Wc fragments held in
//  REGISTERS (no sB in LDS), bias in registers.
//  GEMM R[b,tf] = image@Wc + bc via mfma_f32_16x16x32_bf16;
//  C-frag: row(b)=quad*4+reg, col(tf within tile)=lane&15 (f = which*16+n).
//  feat0/feat1/vectors double-buffered one b-tile ahead (global, L1/L2-hot).
//  Each output slot is produced by one wave x 4 quads -> 4-copy LDS reduce.
// LDS: sA [256][72] bf16 = 36864 B; red[352][5] f32 (7040 B) aliases sA.
// 4 blocks/CU (147.5 KiB), whole 1024-block grid co-resident.
// ---------------------------------------------------------------------------
__global__ __launch_bounds__(256, 4) void conv_main(
    const float* __restrict__ image, const float* __restrict__ vectors,
    const float* __restrict__ feat0, const float* __restrict__ feat1,
    const unsigned short* __restrict__ wsT, const float* __restrict__ bcw,
    const float* __restrict__ w_si0, const float* __restrict__ w_si1,
    const float* __restrict__ b_act0, const float* __restrict__ b_act1,
    float* __restrict__ out)
{
  __shared__ __align__(16) char smem[36864];
  unsigned short* sA  = (unsigned short*)smem;   // [256][72] bf16
  float*          red = (float*)smem;            // [352][5] alias after compute

  const int t    = threadIdx.x;
  const int m    = blockIdx.x >> 8;
  const int a    = blockIdx.x & 255;
  const int w    = t >> 6;
  const int l    = t & 63;
  const int n    = l & 15;
  const int quad = l >> 4;
  const int which   = w & 1;
  const int pairsel = ((w >> 1) ^ blockIdx.x) & 1;
  const int tagA = pairsel ? 1 : 0;       // pair0: {00,11}, pair1: {01,10}
  const int tagB = pairsel ? 2 : 3;
  const int ctA  = tagA * 2 + which;
  const int ctB  = tagB * 2 + which;
  const int f    = which * 16 + n;        // feature column this lane owns

  // ---- Wc fragments + bias into registers (global, L2-resident) ----
  const unsigned short* wrA = wsT + (ctA * 16 + n) * 64 + quad * 8;
  const unsigned short* wrB = wsT + (ctB * 16 + n) * 64 + quad * 8;
  const bf16x8 wA0 = *(const bf16x8*)(wrA);
  const bf16x8 wA1 = *(const bf16x8*)(wrA + 32);
  const bf16x8 wB0 = *(const bf16x8*)(wrB);
  const bf16x8 wB1 = *(const bf16x8*)(wrB + 32);
  const float  bcA = bcw[ctA * 16 + n];
  const float  bcB = bcw[ctB * 16 + n];

  // ---- stage full image row-block (256 b x 64 rbf) to LDS as bf16 ----
  const float* imgMA = image + ((size_t)(m * A_ + a)) * A_ * RBF_;
  #pragma unroll
  for (int i = 0; i < 8; ++i) {
    int g = t + 256 * i;            // 0..2047 groups of 8 elems
    int r = g >> 3, c8 = g & 7;
    const float* src = imgMA + r * RBF_ + c8 * 8;
    float4 v0 = *(const float4*)(src);
    float4 v1 = *(const float4*)(src + 4);
    uint4 pk;
    pk.x = pack2bf(v0.x, v0.y);
    pk.y = pack2bf(v0.z, v0.w);
    pk.z = pack2bf(v1.x, v1.y);
    pk.w = pack2bf(v1.z, v1.w);
    *(uint4*)&sA[r * 72 + c8 * 8] = pk;
  }

  // ---- lane-private operand pointers ----
  const float* p0 = feat0 + (size_t)(m * A_) * F_ + f;          // + b*F_
  const float* p1 = feat1 + ((size_t)(m * A_) * F_ + f) * 3;    // + b*96
  const float* pv = vectors + ((size_t)(m * A_ + a)) * A_ * 3;  // + b*3

  float ft0[2][4], gg[2][3][4], vv[2][3][4];
  float pS0 = 0.f, pS1 = 0.f, pV0 = 0.f, pV1 = 0.f, pV2 = 0.f;
  float pW0 = 0.f, pW1 = 0.f, pW2 = 0.f;

#define PF(BUF, BT) { \
    const int b0 = (BT) * 16 + quad * 4; \
    _Pragma("unroll") \
    for (int r = 0; r < 4; ++r) { \
      ft0[BUF][r] = p0[(b0 + r) * F_]; \
      const float* fp = p1 + (size_t)(b0 + r) * (F_ * 3); \
      gg[BUF][0][r] = fp[0]; gg[BUF][1][r] = fp[1]; gg[BUF][2][r] = fp[2]; \
      const float* vp = pv + (b0 + r) * 3; \
      vv[BUF][0][r] = vp[0]; vv[BUF][1][r] = vp[1]; vv[BUF][2][r] = vp[2]; \
    } }

#define BODY(BT, BUF) { \
    const int brow = (BT) * 16; \
    const bf16x8 a0 = *(const bf16x8*)&sA[(brow + n) * 72 + quad * 8]; \
    const bf16x8 a1 = *(const bf16x8*)&sA[(brow + n) * 72 + 32 + quad * 8]; \
    f32x4 accA = {bcA, bcA, bcA, bcA}; \
    f32x4 accB = {bcB, bcB, bcB, bcB}; \
    accA = __builtin_amdgcn_mfma_f32_16x16x32_bf16(a0, wA0, accA, 0, 0, 0); \
    accA = __builtin_amdgcn_mfma_f32_16x16x32_bf16(a1, wA1, accA, 0, 0, 0); \
    accB = __builtin_amdgcn_mfma_f32_16x16x32_bf16(a0, wB0, accB, 0, 0, 0); \
    accB = __builtin_amdgcn_mfma_f32_16x16x32_bf16(a1, wB1, accB, 0, 0, 0); \
    if (pairsel == 0) {            /* accA -> tag00, accB -> tag11 */ \
      _Pragma("unroll") \
      for (int r = 0; r < 4; ++r) pS0 += accA[r] * ft0[BUF][r]; \
      _Pragma("unroll") \
      for (int r = 0; r < 4; ++r) { \
        const float Rr = accB[r]; \
        const float gx = gg[BUF][0][r], gy = gg[BUF][1][r], gz = gg[BUF][2][r]; \
        const float ux = vv[BUF][0][r], uy = vv[BUF][1][r], uz = vv[BUF][2][r]; \
        pS1 += Rr * (ux * gx + uy * gy + uz * gz); \
        pV0 += Rr * (uy * gz - uz * gy); \
        pV1 += Rr * (uz * gx - ux * gz); \
        pV2 += Rr * (ux * gy - uy * gx); \
      } \
    } else {                       /* accA -> tag01, accB -> tag10 */ \
      _Pragma("unroll") \
      for (int r = 0; r < 4; ++r) { \
        const float s = accA[r] * ft0[BUF][r]; \
        pV0 += vv[BUF][0][r] * s; \
        pV1 += vv[BUF][1][r] * s; \
        pV2 += vv[BUF][2][r] * s; \
        const float Rb = accB[r]; \
        pW0 += Rb * gg[BUF][0][r]; \
        pW1 += Rb * gg[BUF][1][r]; \
        pW2 += Rb * gg[BUF][2][r]; \
      } \
    } }

  PF(0, 0)
  __syncthreads();

  #pragma unroll 1
  for (int bth = 0; bth < 8; ++bth) {
    const int bt0 = bth * 2;
    PF(1, bt0 + 1)        // issue next-tile loads before consuming current
    BODY(bt0, 0)
    if (bth < 7) PF(0, bt0 + 2)
    BODY(bt0 + 1, 1)
  }

  __syncthreads();   // sA fully consumed -> red alias is safe

  // ---- write 4-copy partials (one owning wave per slot, copies = quads) ----
  // slots: out000: f | out110: 32+f | out011: 64+f*3+d
  //        out101: 160+f*3+d | out111: 256+f*3+d      (total 352)
  if (pairsel == 0) {
    red[f * 5 + quad]                 = pS0;
    red[(32 + f) * 5 + quad]          = pS1;
    red[(256 + f * 3 + 0) * 5 + quad] = pV0;
    red[(256 + f * 3 + 1) * 5 + quad] = pV1;
    red[(256 + f * 3 + 2) * 5 + quad] = pV2;
  } else {
    red[(64 + f * 3 + 0) * 5 + quad]  = pV0;
    red[(64 + f * 3 + 1) * 5 + quad]  = pV1;
    red[(64 + f * 3 + 2) * 5 + quad]  = pV2;
    red[(160 + f * 3 + 0) * 5 + quad] = pW0;
    red[(160 + f * 3 + 1) * 5 + quad] = pW1;
    red[(160 + f * 3 + 2) * 5 + quad] = pW2;
  }
  __syncthreads();

  for (int s = t; s < 352; s += 256)
    red[s * 5 + 4] = red[s * 5 + 0] + red[s * 5 + 1] +
                     red[s * 5 + 2] + red[s * 5 + 3];
  __syncthreads();

  // ---- self-interaction + equivariant activation epilogue ----
  // cat0[i] = red[i*5+4] (i<64: out000|out110)
  // cat1[i] = red[(64+i)*5+4] (i<288: out011|out101|out111, (row,d) packed)
  const int outBase = (m * A_ + a) * SI_;
  if (t < 32) {
    const float* wr = w_si0 + t * 64;
    float s = 0.f;
    #pragma unroll 8
    for (int ff = 0; ff < 64; ++ff) s += red[ff * 5 + 4] * wr[ff];
    s += b_act0[t];
    out[outBase + t] = sspf(s);
  } else if (t >= 64 && t < 96) {
    int g = t - 64;
    const float* wr = w_si1 + g * 96;
    float s0 = 0.f, s1 = 0.f, s2 = 0.f;
    #pragma unroll 8
    for (int ff = 0; ff < 96; ++ff) {
      float wv = wr[ff];
      s0 += red[(64 + ff * 3 + 0) * 5 + 4] * wv;
      s1 += red[(64 + ff * 3 + 1) * 5 + 4] * wv;
      s2 += red[(64 + ff * 3 + 2) * 5 + 4] * wv;
    }
    float n2 = s0 * s0 + s1 * s1 + s2 * s2;
    float n1 = sqrtf(fmaxf(n2, 1e-7f));     // norm_with_epsilon, EPS=1e-7
    float a1 = sspf(n1 + b_act1[g]);
    float sc = a1 / n1;
    int ob = M_ * A_ * SI_ + (outBase + g) * 3;   // o0 is 32768 floats
    out[ob + 0] = s0 * sc;
    out[ob + 1] = s1 * sc;
    out[ob + 2] = s2 * sc;
  }
}

extern "C" void kernel_launch(void* const* d_in, const int* in_sizes, int n_in,
                              void* d_out, int out_size, void* d_ws, size_t ws_size,
                              hipStream_t stream) {
  const float* image   = (const float*)d_in[0];
  const float* vectors = (const float*)d_in[1];
  const float* feat0   = (const float*)d_in[2];
  const float* feat1   = (const float*)d_in[3];
  const float* w_si0   = (const float*)d_in[20];
  const float* w_si1   = (const float*)d_in[21];
  const float* b_act0  = (const float*)d_in[22];
  const float* b_act1  = (const float*)d_in[23];
  unsigned short* wsT = (unsigned short*)d_ws;           // 128*64 bf16 = 16384 B
  float* bcw = (float*)((char*)d_ws + 16384);            // 128 f32
  float* out = (float*)d_out;

  combine_weights<<<32, 256, 0, stream>>>(
      (const float*)d_in[4],  (const float*)d_in[5],
      (const float*)d_in[6],  (const float*)d_in[7],
      (const float*)d_in[8],  (const float*)d_in[9],
      (const float*)d_in[10], (const float*)d_in[11],
      (const float*)d_in[12], (const float*)d_in[13],
      (const float*)d_in[14], (const float*)d_in[15],
      (const float*)d_in[16], (const float*)d_in[17],
      (const float*)d_in[18], (const float*)d_in[19],
      wsT, bcw);

  conv_main<<<M_ * A_, 256, 0, stream>>>(
      image, vectors, feat0, feat1, wsT, bcw,
      w_si0, w_si1, b_act0, b_act1, out);
}